// Round 7
// baseline (202.129 us; speedup 1.0000x reference)
//
#include <hip/hip_runtime.h>
#include <hip/hip_bf16.h>

// Problem constants
#define B_SZ 256
#define SDIM 1024
#define ADIM 512

#define BKW 64               // k-chunk (f32 elems) per stage
#define NCH (SDIM / BKW)     // 16

typedef __attribute__((ext_vector_type(8))) short bf16x8;
typedef __attribute__((ext_vector_type(4))) float f32x4;

__device__ __forceinline__ unsigned short f2bf(float x) {
  union { float f; unsigned u; } v; v.f = x;
  unsigned r = v.u + 0x7FFFu + ((v.u >> 16) & 1u);   // round-to-nearest-even
  return (unsigned short)(r >> 16);
}

__device__ __forceinline__ void gll16(const void* g, void* l) {
  __builtin_amdgcn_global_load_lds(
      (const __attribute__((address_space(1))) unsigned int*)g,
      (__attribute__((address_space(3))) unsigned int*)l, 16, 0, 0);
}

__device__ __forceinline__ unsigned cvtpk(float lo, float hi) {
  unsigned r;
  asm("v_cvt_pk_bf16_f32 %0, %1, %2" : "=v"(r) : "v"(lo), "v"(hi));
  return r;
}

// ---------------- Kernel 1: small MLPs + obs->bf16 fragment layout + cw2b dot --------
__global__ __launch_bounds__(128) void kprep(
    const float* __restrict__ obs,
    const float* __restrict__ task, const int* __restrict__ action,
    const float* __restrict__ we1, const float* __restrict__ be1,
    const float* __restrict__ we2, const float* __restrict__ be2,
    const float* __restrict__ aw1, const float* __restrict__ aw1b,
    const float* __restrict__ ab1, const float* __restrict__ ab1b,
    const float* __restrict__ ab2, const float* __restrict__ ab2b,
    const float* __restrict__ cw1, const float* __restrict__ cw1b,
    const float* __restrict__ cb1, const float* __restrict__ cb1b,
    const float* __restrict__ cb2, const float* __restrict__ cb2b,
    const float* __restrict__ cw2b,
    float* __restrict__ ws_ha, float* __restrict__ ws_hc,
    unsigned short* __restrict__ obsT,
    float* __restrict__ out)
{
  const int b = blockIdx.x, t = threadIdx.x;
  __shared__ float s_task[64], s_t1[64], s_z[64], s_hb[128], s_red[128];

  // obs row b -> fragment-ordered bf16 obsT; slot t: kc=t>>2, g=t&3 covers k=kc*32+g*8..+8
  // obsT ushort index: ((kc*256 + b)*4 + g)*8  -> af reads become contiguous 1KB per instr
  float dotc = 0.0f;
  {
    const int kc = t >> 2, g = t & 3;
    const float4* src = (const float4*)(obs + (size_t)b * SDIM + kc * 32 + g * 8);
    const float4* cbp = (const float4*)(cw2b + kc * 32 + g * 8);
    float4 x = src[0], y = src[1];
    float4 c0 = cbp[0], c1 = cbp[1];
    dotc = x.x * c0.x + x.y * c0.y + x.z * c0.z + x.w * c0.w
         + y.x * c1.x + y.y * c1.y + y.z * c1.z + y.w * c1.w;
    ushort4 u0, u1;
    u0.x = f2bf(x.x); u0.y = f2bf(x.y); u0.z = f2bf(x.z); u0.w = f2bf(x.w);
    u1.x = f2bf(y.x); u1.y = f2bf(y.y); u1.z = f2bf(y.z); u1.w = f2bf(y.w);
    ushort4* d = (ushort4*)(obsT + ((size_t)(kc * 256 + b) * 4 + g) * 8);
    d[0] = u0; d[1] = u1;
  }

  if (t < 64) s_task[t] = task[b * 64 + t];
  __syncthreads();
  if (t < 64) {
    float a = be1[t];
    for (int e = 0; e < 64; ++e) a += s_task[e] * we1[e * 64 + t];
    s_t1[t] = fmaxf(a, 0.0f);
  }
  __syncthreads();
  if (t < 64) {
    float a = be2[t];
    for (int e = 0; e < 64; ++e) a += s_t1[e] * we2[e * 64 + t];
    s_z[t] = fmaxf(a, 0.0f);
  }
  __syncthreads();
  {
    float a1 = aw1b[t], a2 = ab1b[t], a3 = cw1b[t], a4 = cb1b[t];
    for (int e = 0; e < 64; ++e) {
      const float zv = s_z[e];
      a1 += zv * aw1[e * 128 + t];
      a2 += zv * ab1[e * 128 + t];
      a3 += zv * cw1[e * 128 + t];
      a4 += zv * cb1[e * 128 + t];
    }
    ws_ha[b * 128 + t] = fmaxf(a1, 0.0f);
    s_hb[t] = fmaxf(a2, 0.0f);
    ws_hc[b * 128 + t] = fmaxf(a3, 0.0f);
    s_red[t] = fmaxf(a4, 0.0f) * cb2[t] + dotc;   // bv partial + cw2b.obs partial
  }
  __syncthreads();
  // ba -> staged into d_out logits slots (khyper atomically accumulates on top)
  for (int o = t; o < ADIM; o += 128) {
    float a = ab2b[o];
    for (int h = 0; h < 128; ++h) a += s_hb[h] * ab2[h * ADIM + o];
    out[b * ADIM + o] = a;
  }
  // bv + cw2b.obs reduction
  for (int s = 64; s > 0; s >>= 1) {
    __syncthreads();
    if (t < s) s_red[t] += s_red[t + s];
  }
  if (t == 0) {
    out[131840 + b] = s_red[0] + cb2b[0];      // v partial; critic blocks add rest
    out[131072 + b] = (float)action[b];        // action as float
  }
}

// ---------------- Kernel 2: occupancy-first hypernet GEMM ----------------
// Skinny blocks: N=32 W-rows, M=256, K=1024. 16 KB LDS, target 64 VGPR ->
// 32 waves/CU. W staged f32 via 1 gll16/thread/chunk (seg-XOR swizzled src);
// obs fragments read per-step from L2-resident fragment-ordered obsT.
__global__ __launch_bounds__(512, 8) void khyper(
    const unsigned short* __restrict__ obsT,
    const float* __restrict__ aw2, const float* __restrict__ aw2b,
    const float* __restrict__ cw2,
    const float* __restrict__ ws_ha, const float* __restrict__ ws_hc,
    float* __restrict__ d_out)
{
  __shared__ float Wl[2][32 * BKW];   // 2 x 8 KB

  const int tid = threadIdx.x;
  const int blk = blockIdx.x;

  // Roles: 0..2047 actor (o = blk>>2, h-quarter = blk&3); 2048..2063 bias; 2064..2067 critic
  int wtype, o0 = 0, h0 = 0;
  const float* Wbase;
  size_t wstride;
  if (blk < 2048) {
    wtype = 0; o0 = blk >> 2; h0 = (blk & 3) * 32;
    Wbase = aw2 + (size_t)h0 * ADIM * SDIM + (size_t)o0 * SDIM;
    wstride = (size_t)ADIM * SDIM;
  } else if (blk < 2064) {
    wtype = 1; o0 = (blk - 2048) * 32;
    Wbase = aw2b + (size_t)o0 * SDIM; wstride = SDIM;
  } else {
    wtype = 2; h0 = (blk - 2064) * 32;
    Wbase = cw2 + (size_t)h0 * SDIM; wstride = SDIM;
  }

  // W staging: thread -> (row = tid>>4, seg = tid&15), source seg XOR-swizzled
  const int srow = tid >> 4, sseg = tid & 15;
  const float* wsrc = Wbase + (size_t)srow * wstride + ((sseg ^ (srow & 7)) << 2);
  const int wv = tid >> 6, lane = tid & 63;
  char* ldst = (char*)(&Wl[0][0]) + wv * 1024;    // + buf*8192; HW adds lane*16

  const int lrow = lane & 15, grp = lane >> 4;
  const int mbase = (wv & 3) * 64;                // 4 M-groups over b=256
  const int nloc = (wv >> 2) * 16 + lrow;         // 0..31: W row within slab

  // af pointer (ushort units); advances 8192 ushorts (16 KB) per k-step
  const unsigned short* pA = obsT + ((size_t)(mbase + lrow) * 4 + grp) * 8;

  // W LDS read byte offsets (within 8 KB buf) per (ks, q):
  // row nloc, col byte = ks*128 + grp*32 + q*16, XOR ((nloc&7)<<4)  -> 2-way banks (free)
  int wb[2][2];
#pragma unroll
  for (int ks = 0; ks < 2; ++ks)
#pragma unroll
    for (int q = 0; q < 2; ++q)
      wb[ks][q] = nloc * 256 + ((ks * 128 + grp * 32 + q * 16) ^ ((nloc & 7) << 4));

  f32x4 acc[4];
#pragma unroll
  for (int mf = 0; mf < 4; ++mf) acc[mf] = (f32x4)(0.0f);

  auto STAGE = [&](int c, int buf) {
    gll16(wsrc + (size_t)c * BKW, ldst + buf * 8192);
  };

  auto COMPUTE = [&](int buf) {
    const char* wl = (const char*)(&Wl[0][0]) + buf * 8192;
#pragma unroll
    for (int ks = 0; ks < 2; ++ks) {
      // B-frag: 8 f32 -> bf16x8
      float4 x = *(const float4*)(wl + wb[ks][0]);
      float4 y = *(const float4*)(wl + wb[ks][1]);
      union { bf16x8 v; unsigned u[4]; } q;
      q.u[0] = cvtpk(x.x, x.y);
      q.u[1] = cvtpk(x.z, x.w);
      q.u[2] = cvtpk(y.x, y.y);
      q.u[3] = cvtpk(y.z, y.w);
      // A-frags: contiguous 1KB per instr from obsT (L1/L2)
      bf16x8 a0 = *(const bf16x8*)(pA);
      bf16x8 a1 = *(const bf16x8*)(pA + 512);
      bf16x8 a2 = *(const bf16x8*)(pA + 1024);
      bf16x8 a3 = *(const bf16x8*)(pA + 1536);
      acc[0] = __builtin_amdgcn_mfma_f32_16x16x32_bf16(a0, q.v, acc[0], 0, 0, 0);
      acc[1] = __builtin_amdgcn_mfma_f32_16x16x32_bf16(a1, q.v, acc[1], 0, 0, 0);
      acc[2] = __builtin_amdgcn_mfma_f32_16x16x32_bf16(a2, q.v, acc[2], 0, 0, 0);
      acc[3] = __builtin_amdgcn_mfma_f32_16x16x32_bf16(a3, q.v, acc[3], 0, 0, 0);
      pA += 8192;                       // next k-step (16 KB)
    }
  };

  STAGE(0, 0);
  __syncthreads();
#pragma unroll 1
  for (int c = 0; c < NCH; ++c) {
    if (c + 1 < NCH) STAGE(c + 1, (c + 1) & 1);
    COMPUTE(c & 1);
    __syncthreads();   // drains gll(c+1) + protects buf reuse; TLP covers the stall
  }

  // ---- epilogue (r6-verified mapping: b = mbase+mf*16+grp*4+r, n = nloc) ----
  if (wtype == 1) {
    const int o = o0 + nloc;
#pragma unroll
    for (int mf = 0; mf < 4; ++mf) {
      const int b = mbase + mf * 16 + grp * 4;
#pragma unroll
      for (int r = 0; r < 4; ++r)
        atomicAdd(&d_out[(size_t)(b + r) * ADIM + o], acc[mf][r]);
    }
  } else {
    const float* hw = (wtype == 0) ? ws_ha : ws_hc;
    const int h = h0 + nloc;
#pragma unroll
    for (int mf = 0; mf < 4; ++mf) {
      const int b = mbase + mf * 16 + grp * 4;
      float val[4];
#pragma unroll
      for (int r = 0; r < 4; ++r)
        val[r] = hw[(size_t)(b + r) * 128 + h] * acc[mf][r];
#pragma unroll
      for (int r = 0; r < 4; ++r) {
        float v = val[r];
        v += __shfl_xor(v, 1, 64);
        v += __shfl_xor(v, 2, 64);
        v += __shfl_xor(v, 4, 64);
        v += __shfl_xor(v, 8, 64);
        val[r] = v;
      }
      if (lrow == 0) {
#pragma unroll
        for (int r = 0; r < 4; ++r) {
          if (wtype == 0) atomicAdd(&d_out[(size_t)(b + r) * ADIM + o0], val[r]);
          else            atomicAdd(&d_out[131840 + b + r], val[r]);
        }
      }
    }
  }
}

// ---------------- Kernel 3: log_softmax / entropy / log_prob ----------------
__global__ __launch_bounds__(256) void kfinal(const int* __restrict__ action,
                                              float* __restrict__ d_out)
{
  const int b = blockIdx.x, t = threadIdx.x;
  const float* lrow = d_out + (size_t)b * ADIM;
  __shared__ float sM[4], sS[4], sT[4];

  const float x0 = lrow[t], x1 = lrow[t + 256];
  float m = fmaxf(x0, x1);
#pragma unroll
  for (int s = 1; s < 64; s <<= 1) m = fmaxf(m, __shfl_xor(m, s, 64));
  const int wv = t >> 6, ln = t & 63;
  if (ln == 0) sM[wv] = m;
  __syncthreads();
  m = fmaxf(fmaxf(sM[0], sM[1]), fmaxf(sM[2], sM[3]));

  const float d0 = x0 - m, d1 = x1 - m;
  const float e0 = expf(d0), e1 = expf(d1);
  float s1 = e0 + e1;
  float s2 = e0 * d0 + e1 * d1;
#pragma unroll
  for (int s = 1; s < 64; s <<= 1) {
    s1 += __shfl_xor(s1, s, 64);
    s2 += __shfl_xor(s2, s, 64);
  }
  if (ln == 0) { sS[wv] = s1; sT[wv] = s2; }
  __syncthreads();
  if (t == 0) {
    const float S = sS[0] + sS[1] + sS[2] + sS[3];
    const float T = sT[0] + sT[1] + sT[2] + sT[3];
    const float lnS = logf(S);
    const int a = action[b];
    d_out[131328 + b] = (lrow[a] - m) - lnS;   // log_prob
    d_out[131584 + b] = lnS - T / S;           // entropy
  }
}

extern "C" void kernel_launch(void* const* d_in, const int* in_sizes, int n_in,
                              void* d_out_v, int out_size, void* d_ws, size_t ws_size,
                              hipStream_t stream) {
  const float* obs   = (const float*)d_in[0];
  const float* task  = (const float*)d_in[1];
  const int*   action= (const int*)  d_in[2];
  const float* we1   = (const float*)d_in[3];
  const float* be1   = (const float*)d_in[4];
  const float* we2   = (const float*)d_in[5];
  const float* be2   = (const float*)d_in[6];
  const float* aw1   = (const float*)d_in[7];
  const float* aw1b  = (const float*)d_in[8];
  const float* aw2   = (const float*)d_in[9];
  const float* aw2b  = (const float*)d_in[10];
  const float* ab1   = (const float*)d_in[11];
  const float* ab1b  = (const float*)d_in[12];
  const float* ab2   = (const float*)d_in[13];
  const float* ab2b  = (const float*)d_in[14];
  const float* cw1   = (const float*)d_in[15];
  const float* cw1b  = (const float*)d_in[16];
  const float* cw2   = (const float*)d_in[17];
  const float* cw2b  = (const float*)d_in[18];
  const float* cb1   = (const float*)d_in[19];
  const float* cb1b  = (const float*)d_in[20];
  const float* cb2   = (const float*)d_in[21];
  const float* cb2b  = (const float*)d_in[22];
  float* out = (float*)d_out_v;
  float* ws_ha = (float*)d_ws;                        // [256][128] f32
  float* ws_hc = ws_ha + 256 * 128;                   // [256][128] f32
  unsigned short* obsT = (unsigned short*)(ws_hc + 256 * 128);  // [32][256][4][8] bf16

  kprep<<<256, 128, 0, stream>>>(obs, task, action, we1, be1, we2, be2, aw1, aw1b,
                                 ab1, ab1b, ab2, ab2b, cw1, cw1b, cb1, cb1b,
                                 cb2, cb2b, cw2b, ws_ha, ws_hc, obsT, out);
  // 2048 actor + 16 bias + 4 critic
  khyper<<<2068, 512, 0, stream>>>(obsT, aw2, aw2b, cw2, ws_ha, ws_hc, out);
  kfinal<<<256, 256, 0, stream>>>(action, out);
}

// Round 8
// 190.182 us; speedup vs baseline: 1.0628x; 1.0628x over previous
//
#include <hip/hip_runtime.h>
#include <hip/hip_bf16.h>

// Problem constants
#define B_SZ 256
#define SDIM 1024
#define ADIM 512

typedef __attribute__((ext_vector_type(8))) short bf16x8;
typedef __attribute__((ext_vector_type(4))) float f32x4;

__device__ __forceinline__ unsigned short f2bf(float x) {
  union { float f; unsigned u; } v; v.f = x;
  unsigned r = v.u + 0x7FFFu + ((v.u >> 16) & 1u);   // round-to-nearest-even
  return (unsigned short)(r >> 16);
}

__device__ __forceinline__ void gll16(const void* g, void* l) {
  __builtin_amdgcn_global_load_lds(
      (const __attribute__((address_space(1))) unsigned int*)g,
      (__attribute__((address_space(3))) unsigned int*)l, 16, 0, 0);
}

__device__ __forceinline__ unsigned cvtpk(float lo, float hi) {
  unsigned r;
  asm("v_cvt_pk_bf16_f32 %0, %1, %2" : "=v"(r) : "v"(lo), "v"(hi));
  return r;
}

// ---------------- Kernel 1: small MLPs + obsT fragment layout + cw2b dot ----------------
// obsT layout: [32 kc][4 g][256 b][8] bf16  (k = kc*32 + g*8 + j)
__global__ __launch_bounds__(128) void kprep(
    const float* __restrict__ obs,
    const float* __restrict__ task, const int* __restrict__ action,
    const float* __restrict__ we1, const float* __restrict__ be1,
    const float* __restrict__ we2, const float* __restrict__ be2,
    const float* __restrict__ aw1, const float* __restrict__ aw1b,
    const float* __restrict__ ab1, const float* __restrict__ ab1b,
    const float* __restrict__ ab2, const float* __restrict__ ab2b,
    const float* __restrict__ cw1, const float* __restrict__ cw1b,
    const float* __restrict__ cb1, const float* __restrict__ cb1b,
    const float* __restrict__ cb2, const float* __restrict__ cb2b,
    const float* __restrict__ cw2b,
    float* __restrict__ ws_ha, float* __restrict__ ws_hc,
    unsigned short* __restrict__ obsT,
    float* __restrict__ out)
{
  const int b = blockIdx.x, t = threadIdx.x;
  __shared__ float s_task[64], s_t1[64], s_z[64], s_hb[128], s_red[128];

  // obs row b -> obsT[kc][g][b][8]; also dot(cw2b, obs[b])
  float dotc = 0.0f;
  {
    const int kc = t >> 2, g = t & 3;
    const float4* src = (const float4*)(obs + (size_t)b * SDIM + kc * 32 + g * 8);
    const float4* cbp = (const float4*)(cw2b + kc * 32 + g * 8);
    float4 x = src[0], y = src[1];
    float4 c0 = cbp[0], c1 = cbp[1];
    dotc = x.x * c0.x + x.y * c0.y + x.z * c0.z + x.w * c0.w
         + y.x * c1.x + y.y * c1.y + y.z * c1.z + y.w * c1.w;
    ushort4 u0, u1;
    u0.x = f2bf(x.x); u0.y = f2bf(x.y); u0.z = f2bf(x.z); u0.w = f2bf(x.w);
    u1.x = f2bf(y.x); u1.y = f2bf(y.y); u1.z = f2bf(y.z); u1.w = f2bf(y.w);
    ushort4* d = (ushort4*)(obsT + ((size_t)(kc * 4 + g) * 256 + b) * 8);
    d[0] = u0; d[1] = u1;
  }

  if (t < 64) s_task[t] = task[b * 64 + t];
  __syncthreads();
  if (t < 64) {
    float a = be1[t];
    for (int e = 0; e < 64; ++e) a += s_task[e] * we1[e * 64 + t];
    s_t1[t] = fmaxf(a, 0.0f);
  }
  __syncthreads();
  if (t < 64) {
    float a = be2[t];
    for (int e = 0; e < 64; ++e) a += s_t1[e] * we2[e * 64 + t];
    s_z[t] = fmaxf(a, 0.0f);
  }
  __syncthreads();
  {
    float a1 = aw1b[t], a2 = ab1b[t], a3 = cw1b[t], a4 = cb1b[t];
    for (int e = 0; e < 64; ++e) {
      const float zv = s_z[e];
      a1 += zv * aw1[e * 128 + t];
      a2 += zv * ab1[e * 128 + t];
      a3 += zv * cw1[e * 128 + t];
      a4 += zv * cb1[e * 128 + t];
    }
    ws_ha[b * 128 + t] = fmaxf(a1, 0.0f);
    s_hb[t] = fmaxf(a2, 0.0f);
    ws_hc[b * 128 + t] = fmaxf(a3, 0.0f);
    s_red[t] = fmaxf(a4, 0.0f) * cb2[t] + dotc;   // bv partial + cw2b.obs partial
  }
  __syncthreads();
  // ba -> staged into d_out logits slots (khyper atomically accumulates on top)
  for (int o = t; o < ADIM; o += 128) {
    float a = ab2b[o];
    for (int h = 0; h < 128; ++h) a += s_hb[h] * ab2[h * ADIM + o];
    out[b * ADIM + o] = a;
  }
  // bv + cw2b.obs reduction
  for (int s = 64; s > 0; s >>= 1) {
    __syncthreads();
    if (t < s) s_red[t] += s_red[t + s];
  }
  if (t == 0) {
    out[131840 + b] = s_red[0] + cb2b[0];      // v partial; critic blocks add rest
    out[131072 + b] = (float)action[b];        // action as float
  }
}

// ---------------- Kernel 2: W-only-VMEM streaming GEMM ----------------
// Actor block: 16 o x 32 h x 128 k. A-slice staged once (gll, conflict-free layout),
// ha in regs, W f32 gll ring-2 (src XOR-swizzled), counted vmcnt, 2 blocks/CU.
__global__ __launch_bounds__(512, 4) void khyper(
    const unsigned short* __restrict__ obsT,
    const float* __restrict__ aw2, const float* __restrict__ aw2b,
    const float* __restrict__ cw2,
    const float* __restrict__ ws_ha, const float* __restrict__ ws_hc,
    float* __restrict__ d_out)
{
  __shared__ unsigned short A_lds[4][4][256][8];   // 64 KB: [kc][g][b][8]
  __shared__ float W_lds[2][32][64];               // 16 KB: [slot][row][64 f32] (u-swizzled)

  const int tid = threadIdx.x;
  const int blk = blockIdx.x;

  int wtype, kq, row0, o0 = 0, nsteps;
  const float* Wbase;
  if (blk < 1024) {            // actor
    wtype = 0;
    o0 = (blk >> 5) * 16;
    row0 = ((blk >> 3) & 3) * 32;
    kq = blk & 7;
    Wbase = aw2;
    nsteps = 32;               // 16 o x 2 k64
  } else if (blk < 1152) {     // bias (aw2b): 32 o-rows x k-eighth
    wtype = 1;
    row0 = ((blk - 1024) >> 3) * 32;
    kq = blk & 7;
    Wbase = aw2b;
    nsteps = 2;
  } else {                     // critic (cw2): 32 h-rows x k-eighth
    wtype = 2;
    row0 = ((blk - 1152) >> 3) * 32;
    kq = blk & 7;
    Wbase = cw2;
    nsteps = 2;
  }
  const int kbase = kq * 128;

  const int wv = tid >> 6, lane = tid & 63;
  const int mq = wv & 3;            // b in [64*mq, 64*mq+64)
  const int hg = wv >> 2;           // row-half (16 rows each)
  const int lrow = lane & 15, grp = lane >> 4;

  // ---- ha/hc into regs FIRST (so loop vmcnt(1) leaves only the newest W gll) ----
  float haR[4][4];
  if (wtype != 1) {
    const float* hsrc = (wtype == 0) ? ws_ha : ws_hc;
    const int h = row0 + hg * 16 + lrow;
#pragma unroll
    for (int mf = 0; mf < 4; ++mf)
#pragma unroll
      for (int r = 0; r < 4; ++r)
        haR[mf][r] = hsrc[(size_t)(mq * 64 + mf * 16 + grp * 4 + r) * 128 + h];
  }

  // ---- A stage: 8 gll16/thread (obsT global layout == LDS layout) ----
  {
    const unsigned short* asrc = obsT + (size_t)kq * 32768;   // 4 kc x 8192 ushorts
    char* adst = (char*)&A_lds[0][0][0][0] + wv * 1024;
#pragma unroll
    for (int i = 0; i < 8; ++i)
      gll16(asrc + ((size_t)i * 512 + tid) * 8, adst + i * 8192);
  }

  // ---- W staging map: thread -> (row=tid>>4, seg=tid&15), source seg XORed ----
  const int srow = tid >> 4;
  const int sgg = ((tid & 15) ^ (srow & 7)) << 2;   // f32 offset within 64
  char* wdst = (char*)&W_lds[0][0][0] + wv * 1024;

  auto STAGE_W = [&](int s) {
    size_t off;
    if (wtype == 0)
      off = ((size_t)(row0 + srow) * ADIM + (o0 + (s >> 1))) * SDIM + kbase + (s & 1) * 64 + sgg;
    else
      off = (size_t)(row0 + srow) * SDIM + kbase + (s & 1) * 64 + sgg;
    gll16(Wbase + off, wdst + (s & 1) * 8192);
  };

  STAGE_W(0);
  STAGE_W(1);

  // ---- fragment read offsets ----
  const int wrow = hg * 16 + lrow;
  int wroff[2][2];   // [kk][quad] byte offsets in slot
#pragma unroll
  for (int kk = 0; kk < 2; ++kk) {
    const int q0 = kk * 8 + grp * 2;
    wroff[kk][0] = wrow * 256 + ((q0 ^ (wrow & 7)) << 4);
    wroff[kk][1] = wrow * 256 + (((q0 + 1) ^ (wrow & 7)) << 4);
  }
  int aoff0[4];      // + kc*16384
#pragma unroll
  for (int mf = 0; mf < 4; ++mf)
    aoff0[mf] = (grp * 256 + mq * 64 + mf * 16 + lrow) * 16;

  f32x4 acc[4];
#pragma unroll
  for (int mf = 0; mf < 4; ++mf) acc[mf] = (f32x4)(0.0f);
  float vacc[4][4];
#pragma unroll
  for (int mf = 0; mf < 4; ++mf)
#pragma unroll
    for (int r = 0; r < 4; ++r) vacc[mf][r] = 0.0f;

  const char* al = (const char*)&A_lds[0][0][0][0];

#pragma unroll 1
  for (int s = 0; s < nsteps; ++s) {
    if (s + 1 < nsteps) asm volatile("s_waitcnt vmcnt(1)" ::: "memory");
    else                asm volatile("s_waitcnt vmcnt(0)" ::: "memory");
    __builtin_amdgcn_s_barrier();
    __builtin_amdgcn_sched_barrier(0);

    // COMPUTE step s (k64 = s&1)
    {
      const char* wl = (const char*)&W_lds[0][0][0] + (s & 1) * 8192;
#pragma unroll
      for (int kk = 0; kk < 2; ++kk) {
        const int kc = (s & 1) * 2 + kk;
        float4 wx = *(const float4*)(wl + wroff[kk][0]);
        float4 wy = *(const float4*)(wl + wroff[kk][1]);
        union { bf16x8 v; unsigned u[4]; } qq;
        qq.u[0] = cvtpk(wx.x, wx.y); qq.u[1] = cvtpk(wx.z, wx.w);
        qq.u[2] = cvtpk(wy.x, wy.y); qq.u[3] = cvtpk(wy.z, wy.w);
#pragma unroll
        for (int mf = 0; mf < 4; ++mf) {
          bf16x8 af = *(const bf16x8*)(al + aoff0[mf] + kc * 16384);
          acc[mf] = __builtin_amdgcn_mfma_f32_16x16x32_bf16(af, qq.v, acc[mf], 0, 0, 0);
        }
      }
    }

    // Actor: per-o reduce every 2nd step, keep result in lane lrow==o_local
    if (wtype == 0 && (s & 1)) {
      const int olocal = s >> 1;
#pragma unroll
      for (int mf = 0; mf < 4; ++mf)
#pragma unroll
        for (int r = 0; r < 4; ++r) {
          float v = haR[mf][r] * acc[mf][r];
          v += __shfl_xor(v, 1, 64);
          v += __shfl_xor(v, 2, 64);
          v += __shfl_xor(v, 4, 64);
          v += __shfl_xor(v, 8, 64);
          if (lrow == olocal) vacc[mf][r] += v;
        }
#pragma unroll
      for (int mf = 0; mf < 4; ++mf) acc[mf] = (f32x4)(0.0f);
    }

    asm volatile("s_waitcnt lgkmcnt(0)" ::: "memory");
    __builtin_amdgcn_sched_barrier(0);
    __builtin_amdgcn_s_barrier();
    if (s + 2 < nsteps) STAGE_W(s + 2);
  }

  // ---- epilogue: coalesced atomicAdd ----
  if (wtype == 0) {
    // lane: b = mq*64+mf*16+grp*4+r, o = o0 + lrow
#pragma unroll
    for (int mf = 0; mf < 4; ++mf)
#pragma unroll
      for (int r = 0; r < 4; ++r)
        atomicAdd(&d_out[(size_t)(mq * 64 + mf * 16 + grp * 4 + r) * ADIM + o0 + lrow],
                  vacc[mf][r]);
  } else if (wtype == 1) {
    // G2[b, o=row0+wrow] directly
#pragma unroll
    for (int mf = 0; mf < 4; ++mf)
#pragma unroll
      for (int r = 0; r < 4; ++r)
        atomicAdd(&d_out[(size_t)(mq * 64 + mf * 16 + grp * 4 + r) * ADIM + row0 + wrow],
                  acc[mf][r]);
  } else {
#pragma unroll
    for (int mf = 0; mf < 4; ++mf)
#pragma unroll
      for (int r = 0; r < 4; ++r) {
        float v = haR[mf][r] * acc[mf][r];
        v += __shfl_xor(v, 1, 64);
        v += __shfl_xor(v, 2, 64);
        v += __shfl_xor(v, 4, 64);
        v += __shfl_xor(v, 8, 64);
        if (lrow == 0)
          atomicAdd(&d_out[131840 + mq * 64 + mf * 16 + grp * 4 + r], v);
      }
  }
}

// ---------------- Kernel 3: log_softmax / entropy / log_prob ----------------
__global__ __launch_bounds__(256) void kfinal(const int* __restrict__ action,
                                              float* __restrict__ d_out)
{
  const int b = blockIdx.x, t = threadIdx.x;
  const float* lrow = d_out + (size_t)b * ADIM;
  __shared__ float sM[4], sS[4], sT[4];

  const float x0 = lrow[t], x1 = lrow[t + 256];
  float m = fmaxf(x0, x1);
#pragma unroll
  for (int s = 1; s < 64; s <<= 1) m = fmaxf(m, __shfl_xor(m, s, 64));
  const int wv = t >> 6, ln = t & 63;
  if (ln == 0) sM[wv] = m;
  __syncthreads();
  m = fmaxf(fmaxf(sM[0], sM[1]), fmaxf(sM[2], sM[3]));

  const float d0 = x0 - m, d1 = x1 - m;
  const float e0 = expf(d0), e1 = expf(d1);
  float s1 = e0 + e1;
  float s2 = e0 * d0 + e1 * d1;
#pragma unroll
  for (int s = 1; s < 64; s <<= 1) {
    s1 += __shfl_xor(s1, s, 64);
    s2 += __shfl_xor(s2, s, 64);
  }
  if (ln == 0) { sS[wv] = s1; sT[wv] = s2; }
  __syncthreads();
  if (t == 0) {
    const float S = sS[0] + sS[1] + sS[2] + sS[3];
    const float T = sT[0] + sT[1] + sT[2] + sT[3];
    const float lnS = logf(S);
    const int a = action[b];
    d_out[131328 + b] = (lrow[a] - m) - lnS;   // log_prob
    d_out[131584 + b] = lnS - T / S;           // entropy
  }
}

extern "C" void kernel_launch(void* const* d_in, const int* in_sizes, int n_in,
                              void* d_out_v, int out_size, void* d_ws, size_t ws_size,
                              hipStream_t stream) {
  const float* obs   = (const float*)d_in[0];
  const float* task  = (const float*)d_in[1];
  const int*   action= (const int*)  d_in[2];
  const float* we1   = (const float*)d_in[3];
  const float* be1   = (const float*)d_in[4];
  const float* we2   = (const float*)d_in[5];
  const float* be2   = (const float*)d_in[6];
  const float* aw1   = (const float*)d_in[7];
  const float* aw1b  = (const float*)d_in[8];
  const float* aw2   = (const float*)d_in[9];
  const float* aw2b  = (const float*)d_in[10];
  const float* ab1   = (const float*)d_in[11];
  const float* ab1b  = (const float*)d_in[12];
  const float* ab2   = (const float*)d_in[13];
  const float* ab2b  = (const float*)d_in[14];
  const float* cw1   = (const float*)d_in[15];
  const float* cw1b  = (const float*)d_in[16];
  const float* cw2   = (const float*)d_in[17];
  const float* cw2b  = (const float*)d_in[18];
  const float* cb1   = (const float*)d_in[19];
  const float* cb1b  = (const float*)d_in[20];
  const float* cb2   = (const float*)d_in[21];
  const float* cb2b  = (const float*)d_in[22];
  float* out = (float*)d_out_v;
  float* ws_ha = (float*)d_ws;                        // [256][128] f32
  float* ws_hc = ws_ha + 256 * 128;                   // [256][128] f32
  unsigned short* obsT = (unsigned short*)(ws_hc + 256 * 128);  // [32][4][256][8] bf16

  kprep<<<256, 128, 0, stream>>>(obs, task, action, we1, be1, we2, be2, aw1, aw1b,
                                 ab1, ab1b, ab2, ab2b, cw1, cw1b, cb1, cb1b,
                                 cb2, cb2b, cw2b, ws_ha, ws_hc, obsT, out);
  // 1024 actor + 128 bias + 32 critic
  khyper<<<1184, 512, 0, stream>>>(obsT, aw2, aw2b, cw2, ws_ha, ws_hc, out);
  kfinal<<<256, 256, 0, stream>>>(action, out);
}